// Round 7
// baseline (505.269 us; speedup 1.0000x reference)
//
#include <hip/hip_runtime.h>
#include <hip/hip_bf16.h>
#include <math.h>

#define N_NODES 100000
#define NFEAT 128
#define NCLASS 16
#define NUM_GRAPHS 64
#define LN_EPS 1e-5f
#define PAD 56   // max in-degree slots; Binomial(1.6M,1e-5) P(>=56) ~1e-9 overall

typedef unsigned int uint;
typedef unsigned short ushort;
typedef short bf16x8 __attribute__((ext_vector_type(8)));
typedef float f32x4 __attribute__((ext_vector_type(4)));

__device__ __forceinline__ float wave_sum64(float v) {
#pragma unroll
    for (int m = 32; m >= 1; m >>= 1) v += __shfl_xor(v, m, 64);
    return v;
}

// bf16 helpers (bit-level, RNE)
__device__ __forceinline__ float bf_lo(uint u) { return __uint_as_float(u << 16); }
__device__ __forceinline__ float bf_hi(uint u) { return __uint_as_float(u & 0xffff0000u); }
__device__ __forceinline__ ushort f2bf(float f) {
    uint u = __float_as_uint(f);
    uint r = 0x7fffu + ((u >> 16) & 1u);
    return (ushort)((u + r) >> 16);
}
__device__ __forceinline__ uint pack2bf(float x, float y) {
    return ((uint)f2bf(y) << 16) | (uint)f2bf(x);
}
// 15-bit float (sign+exp8+mant6), RNE; exact for ew=1.0
__device__ __forceinline__ uint pk15(float f) {
    uint u = __float_as_uint(f);
    uint r = 0xFFFFu + ((u >> 17) & 1u);
    return (u + r) >> 17;
}
__device__ __forceinline__ float up15(uint w) {
    return __uint_as_float((w & 0x7FFFu) << 17);
}

__global__ void k_init0(int* __restrict__ head, float* __restrict__ pooled) {
    int i = blockIdx.x * 256 + threadIdx.x;
    if (i < N_NODES) head[i] = -1;
    if (i < NUM_GRAPHS * NFEAT) pooled[i] = 0.0f;
}

// linked-list build: next[e] = old head of dst chain. One int atomic
// (L2-merging) + one fully coalesced 4B store per edge.
__global__ void k_fill_ll(const int* __restrict__ dst, int* __restrict__ head,
                          int* __restrict__ next, int E) {
    int e = blockIdx.x * 256 + threadIdx.x;
    if (e >= E) return;
    next[e] = atomicExch(&head[dst[e]], e);
}

// one thread per node: walk chain, emit compact rowcsr records, compute
// dinv and cnt. Chain loads are dependent but 100k threads run in parallel.
__global__ void k_prep_ll(const int* __restrict__ head, const int* __restrict__ next,
                          const int* __restrict__ src, const float* __restrict__ ew,
                          uint* __restrict__ rowcsr, int* __restrict__ cnt,
                          float* __restrict__ dinv, int n) {
    int d = blockIdx.x * 256 + threadIdx.x;
    if (d >= n) return;
    size_t rb = (size_t)d * PAD;
    int e = head[d];
    float s = 0.0f;
    int r = 0;
    while (e >= 0) {
        int en = next[e];          // dependent (critical path)
        int sv = src[e];           // independent
        float w = ew[e];           // independent
        if (r < PAD) rowcsr[rb + r] = ((uint)sv << 15) | pk15(w);
        s += w;
        ++r;
        e = en;
    }
    cnt[d] = (r < PAD) ? r : PAD;
    float deg = 1.0f + s;
    dinv[d] = (deg > 0.0f) ? rsqrtf(deg) : 0.0f;
}

// fp32 [2x 128x128] -> bf16 (both weight matrices in one launch)
__global__ void k_w2b(const float* __restrict__ W1, const float* __restrict__ W2,
                      ushort* __restrict__ Wb) {
    int i = blockIdx.x * 256 + threadIdx.x;
    if (i < NFEAT * NFEAT) Wb[i] = f2bf(W1[i]);
    else if (i < 2 * NFEAT * NFEAT) Wb[i] = f2bf(W2[i - NFEAT * NFEAT]);
}

// LN0: fp32 in -> bf16 out. One wave per row, 2 feats/lane.
__global__ void k_ln0(const float* __restrict__ in, const float* __restrict__ g,
                      const float* __restrict__ b, ushort* __restrict__ out, int n) {
    int row = blockIdx.x * 4 + (threadIdx.x >> 6);
    if (row >= n) return;
    int lane = threadIdx.x & 63;
    float2 v = *(const float2*)(in + (size_t)row * NFEAT + 2 * lane);
    float mean = wave_sum64(v.x + v.y) * (1.0f / NFEAT);
    float dx = v.x - mean, dy = v.y - mean;
    float var = wave_sum64(dx * dx + dy * dy) * (1.0f / NFEAT);
    float rs = rsqrtf(var + LN_EPS);
    float2 gg = *(const float2*)(g + 2 * lane);
    float2 bb = *(const float2*)(b + 2 * lane);
    float ox = dx * rs * gg.x + bb.x;
    float oy = dy * rs * gg.y + bb.y;
    *(uint*)(out + (size_t)row * NFEAT + 2 * lane) = pack2bf(ox, oy);
}

// MFMA GEMM: C[i][:] = bf16( dinv[i] * (A[i][:] @ W^T) )
__global__ __launch_bounds__(256) void k_gemm_mfma(const ushort* __restrict__ A,
                                                   const ushort* __restrict__ Wb,
                                                   const float* __restrict__ dinv,
                                                   ushort* __restrict__ C, int nrows) {
    int tid = threadIdx.x;
    int wave = tid >> 6, lane = tid & 63;
    int row0 = blockIdx.x * 64 + wave * 16;
    int m = lane & 15, q = lane >> 4;   // A/B frag: [m][k=q*8+j]
    int ra = row0 + m;
    bf16x8 a0 = {0,0,0,0,0,0,0,0}, a1 = a0, a2 = a0, a3 = a0;
    if (ra < nrows) {
        const ushort* p = A + (size_t)ra * NFEAT + q * 8;
        a0 = *(const bf16x8*)(p);
        a1 = *(const bf16x8*)(p + 32);
        a2 = *(const bf16x8*)(p + 64);
        a3 = *(const bf16x8*)(p + 96);
    }
    int orow[4];
    float sd[4];
#pragma unroll
    for (int r = 0; r < 4; ++r) {
        orow[r] = row0 + q * 4 + r;
        sd[r] = (orow[r] < nrows) ? dinv[orow[r]] : 0.0f;
    }
#pragma unroll
    for (int t = 0; t < 8; ++t) {
        const ushort* bp = Wb + (size_t)(t * 16 + m) * NFEAT + q * 8;
        bf16x8 b0 = *(const bf16x8*)(bp);
        bf16x8 b1 = *(const bf16x8*)(bp + 32);
        bf16x8 b2 = *(const bf16x8*)(bp + 64);
        bf16x8 b3 = *(const bf16x8*)(bp + 96);
        f32x4 acc = {0.0f, 0.0f, 0.0f, 0.0f};
        acc = __builtin_amdgcn_mfma_f32_16x16x32_bf16(a0, b0, acc, 0, 0, 0);
        acc = __builtin_amdgcn_mfma_f32_16x16x32_bf16(a1, b1, acc, 0, 0, 0);
        acc = __builtin_amdgcn_mfma_f32_16x16x32_bf16(a2, b2, acc, 0, 0, 0);
        acc = __builtin_amdgcn_mfma_f32_16x16x32_bf16(a3, b3, acc, 0, 0, 0);
#pragma unroll
        for (int r = 0; r < 4; ++r) {
            if (orow[r] < nrows)
                C[(size_t)orow[r] * NFEAT + t * 16 + m] = f2bf(acc[r] * sd[r]);
        }
    }
}

// Gather aggregation + LN + ReLU, bf16 rows, 4 B edge meta, x8 unrolled
// gather batches for latency hiding.
__global__ __launch_bounds__(256) void k_agg_ln(const ushort* __restrict__ T,
                                                const uint* __restrict__ rowcsr,
                                                const int* __restrict__ cnt,
                                                const float* __restrict__ dinv,
                                                const float* __restrict__ bias,
                                                const float* __restrict__ lng,
                                                const float* __restrict__ lnb,
                                                ushort* __restrict__ out, int n) {
    int node = blockIdx.x * 4 + (threadIdx.x >> 6);
    if (node >= n) return;
    int lane = threadIdx.x & 63;
    float di = dinv[node];
    uint tu = *(const uint*)(T + (size_t)node * NFEAT + 2 * lane);
    float ax = bf_lo(tu);
    float ay = bf_hi(tu);
    int c = cnt[node];
    if (c > PAD) c = PAD;
    size_t base = (size_t)node * PAD;
    for (int e0 = 0; e0 < c; e0 += 64) {
        int c2 = c - e0;
        if (c2 > 64) c2 = 64;
        uint meta = 0;
        if (lane < c2) meta = rowcsr[base + e0 + lane];
        int j = 0;
        for (; j + 8 <= c2; j += 8) {
            uint mw[8];
#pragma unroll
            for (int k = 0; k < 8; ++k) mw[k] = __shfl(meta, j + k, 64);
            uint uu[8];
#pragma unroll
            for (int k = 0; k < 8; ++k) {
                int s = (int)(mw[k] >> 15);
                uu[k] = *(const uint*)(T + (size_t)s * NFEAT + 2 * lane);
            }
#pragma unroll
            for (int k = 0; k < 8; ++k) {
                float w = up15(mw[k]);
                ax = fmaf(bf_lo(uu[k]), w, ax);
                ay = fmaf(bf_hi(uu[k]), w, ay);
            }
        }
        if (j + 4 <= c2) {
            uint mw[4];
#pragma unroll
            for (int k = 0; k < 4; ++k) mw[k] = __shfl(meta, j + k, 64);
            uint uu[4];
#pragma unroll
            for (int k = 0; k < 4; ++k) {
                int s = (int)(mw[k] >> 15);
                uu[k] = *(const uint*)(T + (size_t)s * NFEAT + 2 * lane);
            }
#pragma unroll
            for (int k = 0; k < 4; ++k) {
                float w = up15(mw[k]);
                ax = fmaf(bf_lo(uu[k]), w, ax);
                ay = fmaf(bf_hi(uu[k]), w, ay);
            }
            j += 4;
        }
        for (; j < c2; ++j) {
            uint mw = __shfl(meta, j, 64);
            int s = (int)(mw >> 15);
            float w = up15(mw);
            uint u = *(const uint*)(T + (size_t)s * NFEAT + 2 * lane);
            ax = fmaf(bf_lo(u), w, ax);
            ay = fmaf(bf_hi(u), w, ay);
        }
    }
    float2 bb = *(const float2*)(bias + 2 * lane);
    float px = fmaf(di, ax, bb.x);
    float py = fmaf(di, ay, bb.y);
    // LN + ReLU
    float mean = wave_sum64(px + py) * (1.0f / NFEAT);
    float dx = px - mean, dy = py - mean;
    float var = wave_sum64(dx * dx + dy * dy) * (1.0f / NFEAT);
    float rs = rsqrtf(var + LN_EPS);
    float2 gg = *(const float2*)(lng + 2 * lane);
    float2 lb = *(const float2*)(lnb + 2 * lane);
    float ox = fmaxf(dx * rs * gg.x + lb.x, 0.0f);
    float oy = fmaxf(dy * rs * gg.y + lb.y, 0.0f);
    *(uint*)(out + (size_t)node * NFEAT + 2 * lane) = pack2bf(ox, oy);
}

// global_add_pool over sorted batch: wave handles 16 consecutive rows,
// flush atomics only on graph change / end.
__global__ __launch_bounds__(256) void k_pool(const ushort* __restrict__ in,
                                              const int* __restrict__ batch,
                                              float* __restrict__ pooled, int n) {
    int wave = blockIdx.x * 4 + (threadIdx.x >> 6);
    int row0 = wave * 16;
    if (row0 >= n) return;
    int lane = threadIdx.x & 63;
    int end = row0 + 16;
    if (end > n) end = n;
    float accx = 0.0f, accy = 0.0f;
    int cur = batch[row0];
    for (int r = row0; r < end; ++r) {
        int g = batch[r];
        if (g != cur) {
            unsafeAtomicAdd(&pooled[cur * NFEAT + 2 * lane], accx);
            unsafeAtomicAdd(&pooled[cur * NFEAT + 2 * lane + 1], accy);
            accx = 0.0f; accy = 0.0f;
            cur = g;
        }
        uint u = *(const uint*)(in + (size_t)r * NFEAT + 2 * lane);
        accx += bf_lo(u);
        accy += bf_hi(u);
    }
    unsafeAtomicAdd(&pooled[cur * NFEAT + 2 * lane], accx);
    unsafeAtomicAdd(&pooled[cur * NFEAT + 2 * lane + 1], accy);
}

// logits = pooled @ Wc^T + bc; log_softmax. One block per graph.
__global__ void k_final(const float* __restrict__ pooled, const float* __restrict__ Wc,
                        const float* __restrict__ bc, float* __restrict__ out) {
    __shared__ float p[128];
    __shared__ float lg[NCLASS];
    int g = blockIdx.x, t = threadIdx.x;
    p[t] = pooled[g * 128 + t];
    __syncthreads();
    if (t < NCLASS) {
        float s = bc[t];
        for (int k = 0; k < 128; ++k) s = fmaf(p[k], Wc[t * 128 + k], s);
        lg[t] = s;
    }
    __syncthreads();
    if (t == 0) {
        float m = -1e30f;
        for (int j = 0; j < NCLASS; ++j) m = fmaxf(m, lg[j]);
        float sum = 0.0f;
        for (int j = 0; j < NCLASS; ++j) sum += expf(lg[j] - m);
        float l = logf(sum);
        for (int j = 0; j < NCLASS; ++j) out[g * NCLASS + j] = lg[j] - m - l;
    }
}

extern "C" void kernel_launch(void* const* d_in, const int* in_sizes, int n_in,
                              void* d_out, int out_size, void* d_ws, size_t ws_size,
                              hipStream_t stream) {
    const float* x    = (const float*)d_in[0];
    const int*   ei   = (const int*)d_in[1];
    const int*   batch= (const int*)d_in[2];
    const float* ew   = (const float*)d_in[3];
    const float* ln0g = (const float*)d_in[4];
    const float* ln0b = (const float*)d_in[5];
    const float* W1   = (const float*)d_in[6];
    const float* b1   = (const float*)d_in[7];
    const float* ln1g = (const float*)d_in[8];
    const float* ln1b = (const float*)d_in[9];
    const float* W2   = (const float*)d_in[10];
    const float* b2   = (const float*)d_in[11];
    const float* ln2g = (const float*)d_in[12];
    const float* ln2b = (const float*)d_in[13];
    const float* Wc   = (const float*)d_in[14];
    const float* bc   = (const float*)d_in[15];
    float* out = (float*)d_out;

    int E = in_sizes[1] / 2;
    const int* srcp = ei;
    const int* dstp = ei + E;

    // ws layout (~81 MB)
    ushort* A     = (ushort*)d_ws;                           // [N,128] bf16
    ushort* B     = A + (size_t)N_NODES * NFEAT;             // [N,128] bf16
    uint*  rowcsr = (uint*)(B + (size_t)N_NODES * NFEAT);    // [N,PAD]
    int*   next   = (int*)(rowcsr + (size_t)N_NODES * PAD);  // [E]
    float* dinv   = (float*)(next + E);                      // [N]
    float* pooled = dinv + N_NODES;                          // [64*128]
    int*   head   = (int*)(pooled + NUM_GRAPHS * NFEAT);     // [N]
    int*   cnt    = head + N_NODES;                          // [N]
    ushort* W1b   = (ushort*)(cnt + N_NODES);                // [128*128] bf16
    ushort* W2b   = W1b + NFEAT * NFEAT;                     // [128*128] bf16

    dim3 blk(256);
    int gN = (N_NODES + 255) / 256;
    int gE = (E + 255) / 256;
    int gW = (N_NODES + 3) / 4;
    int gG = (N_NODES + 63) / 64;

    k_init0<<<gN, blk, 0, stream>>>(head, pooled);
    k_fill_ll<<<gE, blk, 0, stream>>>(dstp, head, next, E);
    k_prep_ll<<<gN, blk, 0, stream>>>(head, next, srcp, ew, rowcsr, cnt, dinv, N_NODES);
    k_w2b<<<128, blk, 0, stream>>>(W1, W2, W1b);

    k_ln0<<<gW, blk, 0, stream>>>(x, ln0g, ln0b, A, N_NODES);
    k_gemm_mfma<<<gG, blk, 0, stream>>>(A, W1b, dinv, B, N_NODES);
    k_agg_ln<<<gW, blk, 0, stream>>>(B, rowcsr, cnt, dinv, b1, ln1g, ln1b, A, N_NODES);
    k_gemm_mfma<<<gG, blk, 0, stream>>>(A, W2b, dinv, B, N_NODES);
    k_agg_ln<<<gW, blk, 0, stream>>>(B, rowcsr, cnt, dinv, b2, ln2g, ln2b, A, N_NODES);
    k_pool<<<(N_NODES + 63) / 64, blk, 0, stream>>>(A, batch, pooled, N_NODES);
    k_final<<<NUM_GRAPHS, dim3(128), 0, stream>>>(pooled, Wc, bc, out);
}

// Round 8
// 409.446 us; speedup vs baseline: 1.2340x; 1.2340x over previous
//
#include <hip/hip_runtime.h>
#include <hip/hip_bf16.h>
#include <math.h>

#define N_NODES 100000
#define NFEAT 128
#define NCLASS 16
#define NUM_GRAPHS 64
#define LN_EPS 1e-5f
#define PAD 56        // max in-degree slots; Binomial(1.6M,1e-5) P(>=56) ~1e-9 overall
#define BSHIFT 7
#define NBKT 782      // ceil(100000/128)
#define BCAP 2560     // bucket capacity; mean 2046, sd ~45 -> +11 sigma
#define EPB 4096      // edges per k_bin block

typedef unsigned int uint;
typedef unsigned short ushort;
typedef short bf16x8 __attribute__((ext_vector_type(8)));
typedef float f32x4 __attribute__((ext_vector_type(4)));

__device__ __forceinline__ float wave_sum64(float v) {
#pragma unroll
    for (int m = 32; m >= 1; m >>= 1) v += __shfl_xor(v, m, 64);
    return v;
}

// bf16 helpers (bit-level, RNE)
__device__ __forceinline__ float bf_lo(uint u) { return __uint_as_float(u << 16); }
__device__ __forceinline__ float bf_hi(uint u) { return __uint_as_float(u & 0xffff0000u); }
__device__ __forceinline__ ushort f2bf(float f) {
    uint u = __float_as_uint(f);
    uint r = 0x7fffu + ((u >> 16) & 1u);
    return (ushort)((u + r) >> 16);
}
__device__ __forceinline__ uint pack2bf(float x, float y) {
    return ((uint)f2bf(y) << 16) | (uint)f2bf(x);
}
// 15-bit float (sign+exp8+mant6), RNE; exact for ew=1.0
__device__ __forceinline__ uint pk15(float f) {
    uint u = __float_as_uint(f);
    uint r = 0xFFFFu + ((u >> 17) & 1u);
    return (u + r) >> 17;
}
__device__ __forceinline__ float up15(uint w) {
    return __uint_as_float((w & 0x7FFFu) << 17);
}

__global__ void k_init0(int* __restrict__ gfill, float* __restrict__ pooled) {
    int i = blockIdx.x * 256 + threadIdx.x;
    if (i < NBKT) gfill[i] = 0;
    if (i < NUM_GRAPHS * NFEAT) pooled[i] = 0.0f;
}

// Bucketed binning: LDS histogram -> one global atomic per (block,bucket)
// run reservation -> grouped run writes into padded bucket buffer.
__global__ __launch_bounds__(256) void k_bin(const int* __restrict__ dst,
                                             const int* __restrict__ src,
                                             const float* __restrict__ ew,
                                             int* __restrict__ gfill,
                                             uint2* __restrict__ binned, int E) {
    __shared__ int lcnt[NBKT];
    __shared__ int lbase[NBKT];
    int t = threadIdx.x;
    int e0 = blockIdx.x * EPB;
    for (int i = t; i < NBKT; i += 256) lcnt[i] = 0;
    __syncthreads();
    int myb[16], myd[16];
#pragma unroll
    for (int i = 0; i < 16; ++i) {
        int e = e0 + i * 256 + t;
        int b = -1, d = 0;
        if (e < E) {
            d = dst[e];
            b = d >> BSHIFT;
            atomicAdd(&lcnt[b], 1);
        }
        myb[i] = b;
        myd[i] = d;
    }
    __syncthreads();
    for (int i = t; i < NBKT; i += 256) {
        int c = lcnt[i];
        lbase[i] = (c > 0) ? atomicAdd(&gfill[i], c) : 0;
        lcnt[i] = 0;  // reuse as local place counter
    }
    __syncthreads();
#pragma unroll
    for (int i = 0; i < 16; ++i) {
        int e = e0 + i * 256 + t;
        if (e >= E) continue;
        int b = myb[i];
        int ofs = lbase[b] + atomicAdd(&lcnt[b], 1);
        if (ofs < BCAP) {
            uint s = (uint)src[e];
            binned[(size_t)b * BCAP + ofs] =
                make_uint2(((uint)(myd[i] & 127) << 17) | s, __float_as_uint(ew[e]));
        }
    }
}

// One block per bucket (128 nodes): scatter records into LDS CSR
// (stride 57 vs bank conflicts), then full-line coalesced copy to global;
// compute cnt + dinv in-block.
__global__ __launch_bounds__(256) void k_build(const uint2* __restrict__ binned,
                                               const int* __restrict__ gfill,
                                               uint* __restrict__ rowcsr,
                                               int* __restrict__ cnt,
                                               float* __restrict__ dinv, int n) {
    __shared__ uint lcsr[128 * 57];   // 29184 B
    __shared__ int lc[128];
    int b = blockIdx.x, t = threadIdx.x;
    int node0 = b << BSHIFT;
    if (t < 128) lc[t] = 0;
    __syncthreads();
    int c = gfill[b];
    if (c > BCAP) c = BCAP;
    const uint2* rec = binned + (size_t)b * BCAP;
    for (int i = t; i < c; i += 256) {
        uint2 r = rec[i];
        int nl = (int)(r.x >> 17);
        int slot = atomicAdd(&lc[nl], 1);
        if (slot < PAD)
            lcsr[nl * 57 + slot] = ((r.x & 0x1FFFFu) << 15) | pk15(__uint_as_float(r.y));
    }
    __syncthreads();
    int nvalid = n - node0;
    if (nvalid > 128) nvalid = 128;
    if (nvalid <= 0) return;
    size_t gbase = (size_t)node0 * PAD;
    int wtot = nvalid * PAD;
    for (int i = t; i < wtot; i += 256) {
        int nl = i / PAD, sl = i - nl * PAD;
        rowcsr[gbase + i] = lcsr[nl * 57 + sl];
    }
    if (t < nvalid) {
        int cc = lc[t];
        if (cc > PAD) cc = PAD;
        float s = 0.0f;
        for (int r = 0; r < cc; ++r) s += up15(lcsr[t * 57 + r]);
        cnt[node0 + t] = cc;
        dinv[node0 + t] = rsqrtf(1.0f + s);
    }
}

// fp32 [2x 128x128] -> bf16 (both weight matrices in one launch)
__global__ void k_w2b(const float* __restrict__ W1, const float* __restrict__ W2,
                      ushort* __restrict__ Wb) {
    int i = blockIdx.x * 256 + threadIdx.x;
    if (i < NFEAT * NFEAT) Wb[i] = f2bf(W1[i]);
    else if (i < 2 * NFEAT * NFEAT) Wb[i] = f2bf(W2[i - NFEAT * NFEAT]);
}

// LN0: fp32 in -> bf16 out. One wave per row, 2 feats/lane.
__global__ void k_ln0(const float* __restrict__ in, const float* __restrict__ g,
                      const float* __restrict__ b, ushort* __restrict__ out, int n) {
    int row = blockIdx.x * 4 + (threadIdx.x >> 6);
    if (row >= n) return;
    int lane = threadIdx.x & 63;
    float2 v = *(const float2*)(in + (size_t)row * NFEAT + 2 * lane);
    float mean = wave_sum64(v.x + v.y) * (1.0f / NFEAT);
    float dx = v.x - mean, dy = v.y - mean;
    float var = wave_sum64(dx * dx + dy * dy) * (1.0f / NFEAT);
    float rs = rsqrtf(var + LN_EPS);
    float2 gg = *(const float2*)(g + 2 * lane);
    float2 bb = *(const float2*)(b + 2 * lane);
    float ox = dx * rs * gg.x + bb.x;
    float oy = dy * rs * gg.y + bb.y;
    *(uint*)(out + (size_t)row * NFEAT + 2 * lane) = pack2bf(ox, oy);
}

// MFMA GEMM: C[i][:] = bf16( dinv[i] * (A[i][:] @ W^T) )
__global__ __launch_bounds__(256) void k_gemm_mfma(const ushort* __restrict__ A,
                                                   const ushort* __restrict__ Wb,
                                                   const float* __restrict__ dinv,
                                                   ushort* __restrict__ C, int nrows) {
    int tid = threadIdx.x;
    int wave = tid >> 6, lane = tid & 63;
    int row0 = blockIdx.x * 64 + wave * 16;
    int m = lane & 15, q = lane >> 4;   // A/B frag: [m][k=q*8+j]
    int ra = row0 + m;
    bf16x8 a0 = {0,0,0,0,0,0,0,0}, a1 = a0, a2 = a0, a3 = a0;
    if (ra < nrows) {
        const ushort* p = A + (size_t)ra * NFEAT + q * 8;
        a0 = *(const bf16x8*)(p);
        a1 = *(const bf16x8*)(p + 32);
        a2 = *(const bf16x8*)(p + 64);
        a3 = *(const bf16x8*)(p + 96);
    }
    int orow[4];
    float sd[4];
#pragma unroll
    for (int r = 0; r < 4; ++r) {
        orow[r] = row0 + q * 4 + r;
        sd[r] = (orow[r] < nrows) ? dinv[orow[r]] : 0.0f;
    }
#pragma unroll
    for (int t = 0; t < 8; ++t) {
        const ushort* bp = Wb + (size_t)(t * 16 + m) * NFEAT + q * 8;
        bf16x8 b0 = *(const bf16x8*)(bp);
        bf16x8 b1 = *(const bf16x8*)(bp + 32);
        bf16x8 b2 = *(const bf16x8*)(bp + 64);
        bf16x8 b3 = *(const bf16x8*)(bp + 96);
        f32x4 acc = {0.0f, 0.0f, 0.0f, 0.0f};
        acc = __builtin_amdgcn_mfma_f32_16x16x32_bf16(a0, b0, acc, 0, 0, 0);
        acc = __builtin_amdgcn_mfma_f32_16x16x32_bf16(a1, b1, acc, 0, 0, 0);
        acc = __builtin_amdgcn_mfma_f32_16x16x32_bf16(a2, b2, acc, 0, 0, 0);
        acc = __builtin_amdgcn_mfma_f32_16x16x32_bf16(a3, b3, acc, 0, 0, 0);
#pragma unroll
        for (int r = 0; r < 4; ++r) {
            if (orow[r] < nrows)
                C[(size_t)orow[r] * NFEAT + t * 16 + m] = f2bf(acc[r] * sd[r]);
        }
    }
}

// Gather aggregation + LN + ReLU, bf16 rows, 4 B edge meta, x8 unrolled
// gather batches for latency hiding.
__global__ __launch_bounds__(256) void k_agg_ln(const ushort* __restrict__ T,
                                                const uint* __restrict__ rowcsr,
                                                const int* __restrict__ cnt,
                                                const float* __restrict__ dinv,
                                                const float* __restrict__ bias,
                                                const float* __restrict__ lng,
                                                const float* __restrict__ lnb,
                                                ushort* __restrict__ out, int n) {
    int node = blockIdx.x * 4 + (threadIdx.x >> 6);
    if (node >= n) return;
    int lane = threadIdx.x & 63;
    float di = dinv[node];
    uint tu = *(const uint*)(T + (size_t)node * NFEAT + 2 * lane);
    float ax = bf_lo(tu);
    float ay = bf_hi(tu);
    int c = cnt[node];
    if (c > PAD) c = PAD;
    size_t base = (size_t)node * PAD;
    for (int e0 = 0; e0 < c; e0 += 64) {
        int c2 = c - e0;
        if (c2 > 64) c2 = 64;
        uint meta = 0;
        if (lane < c2) meta = rowcsr[base + e0 + lane];
        int j = 0;
        for (; j + 8 <= c2; j += 8) {
            uint mw[8];
#pragma unroll
            for (int k = 0; k < 8; ++k) mw[k] = __shfl(meta, j + k, 64);
            uint uu[8];
#pragma unroll
            for (int k = 0; k < 8; ++k) {
                int s = (int)(mw[k] >> 15);
                uu[k] = *(const uint*)(T + (size_t)s * NFEAT + 2 * lane);
            }
#pragma unroll
            for (int k = 0; k < 8; ++k) {
                float w = up15(mw[k]);
                ax = fmaf(bf_lo(uu[k]), w, ax);
                ay = fmaf(bf_hi(uu[k]), w, ay);
            }
        }
        if (j + 4 <= c2) {
            uint mw[4];
#pragma unroll
            for (int k = 0; k < 4; ++k) mw[k] = __shfl(meta, j + k, 64);
            uint uu[4];
#pragma unroll
            for (int k = 0; k < 4; ++k) {
                int s = (int)(mw[k] >> 15);
                uu[k] = *(const uint*)(T + (size_t)s * NFEAT + 2 * lane);
            }
#pragma unroll
            for (int k = 0; k < 4; ++k) {
                float w = up15(mw[k]);
                ax = fmaf(bf_lo(uu[k]), w, ax);
                ay = fmaf(bf_hi(uu[k]), w, ay);
            }
            j += 4;
        }
        for (; j < c2; ++j) {
            uint mw = __shfl(meta, j, 64);
            int s = (int)(mw >> 15);
            float w = up15(mw);
            uint u = *(const uint*)(T + (size_t)s * NFEAT + 2 * lane);
            ax = fmaf(bf_lo(u), w, ax);
            ay = fmaf(bf_hi(u), w, ay);
        }
    }
    float2 bb = *(const float2*)(bias + 2 * lane);
    float px = fmaf(di, ax, bb.x);
    float py = fmaf(di, ay, bb.y);
    // LN + ReLU
    float mean = wave_sum64(px + py) * (1.0f / NFEAT);
    float dx = px - mean, dy = py - mean;
    float var = wave_sum64(dx * dx + dy * dy) * (1.0f / NFEAT);
    float rs = rsqrtf(var + LN_EPS);
    float2 gg = *(const float2*)(lng + 2 * lane);
    float2 lb = *(const float2*)(lnb + 2 * lane);
    float ox = fmaxf(dx * rs * gg.x + lb.x, 0.0f);
    float oy = fmaxf(dy * rs * gg.y + lb.y, 0.0f);
    *(uint*)(out + (size_t)node * NFEAT + 2 * lane) = pack2bf(ox, oy);
}

// global_add_pool over sorted batch: wave handles 16 consecutive rows,
// flush atomics only on graph change / end.
__global__ __launch_bounds__(256) void k_pool(const ushort* __restrict__ in,
                                              const int* __restrict__ batch,
                                              float* __restrict__ pooled, int n) {
    int wave = blockIdx.x * 4 + (threadIdx.x >> 6);
    int row0 = wave * 16;
    if (row0 >= n) return;
    int lane = threadIdx.x & 63;
    int end = row0 + 16;
    if (end > n) end = n;
    float accx = 0.0f, accy = 0.0f;
    int cur = batch[row0];
    for (int r = row0; r < end; ++r) {
        int g = batch[r];
        if (g != cur) {
            unsafeAtomicAdd(&pooled[cur * NFEAT + 2 * lane], accx);
            unsafeAtomicAdd(&pooled[cur * NFEAT + 2 * lane + 1], accy);
            accx = 0.0f; accy = 0.0f;
            cur = g;
        }
        uint u = *(const uint*)(in + (size_t)r * NFEAT + 2 * lane);
        accx += bf_lo(u);
        accy += bf_hi(u);
    }
    unsafeAtomicAdd(&pooled[cur * NFEAT + 2 * lane], accx);
    unsafeAtomicAdd(&pooled[cur * NFEAT + 2 * lane + 1], accy);
}

// logits = pooled @ Wc^T + bc; log_softmax. One block per graph.
__global__ void k_final(const float* __restrict__ pooled, const float* __restrict__ Wc,
                        const float* __restrict__ bc, float* __restrict__ out) {
    __shared__ float p[128];
    __shared__ float lg[NCLASS];
    int g = blockIdx.x, t = threadIdx.x;
    p[t] = pooled[g * 128 + t];
    __syncthreads();
    if (t < NCLASS) {
        float s = bc[t];
        for (int k = 0; k < 128; ++k) s = fmaf(p[k], Wc[t * 128 + k], s);
        lg[t] = s;
    }
    __syncthreads();
    if (t == 0) {
        float m = -1e30f;
        for (int j = 0; j < NCLASS; ++j) m = fmaxf(m, lg[j]);
        float sum = 0.0f;
        for (int j = 0; j < NCLASS; ++j) sum += expf(lg[j] - m);
        float l = logf(sum);
        for (int j = 0; j < NCLASS; ++j) out[g * NCLASS + j] = lg[j] - m - l;
    }
}

extern "C" void kernel_launch(void* const* d_in, const int* in_sizes, int n_in,
                              void* d_out, int out_size, void* d_ws, size_t ws_size,
                              hipStream_t stream) {
    const float* x    = (const float*)d_in[0];
    const int*   ei   = (const int*)d_in[1];
    const int*   batch= (const int*)d_in[2];
    const float* ew   = (const float*)d_in[3];
    const float* ln0g = (const float*)d_in[4];
    const float* ln0b = (const float*)d_in[5];
    const float* W1   = (const float*)d_in[6];
    const float* b1   = (const float*)d_in[7];
    const float* ln1g = (const float*)d_in[8];
    const float* ln1b = (const float*)d_in[9];
    const float* W2   = (const float*)d_in[10];
    const float* b2   = (const float*)d_in[11];
    const float* ln2g = (const float*)d_in[12];
    const float* ln2b = (const float*)d_in[13];
    const float* Wc   = (const float*)d_in[14];
    const float* bc   = (const float*)d_in[15];
    float* out = (float*)d_out;

    int E = in_sizes[1] / 2;
    const int* srcp = ei;
    const int* dstp = ei + E;

    // ws layout (~90 MB)
    ushort* A     = (ushort*)d_ws;                            // [N,128] bf16
    ushort* B     = A + (size_t)N_NODES * NFEAT;              // [N,128] bf16
    uint*  rowcsr = (uint*)(B + (size_t)N_NODES * NFEAT);     // [N,PAD] 22.4 MB
    uint2* binned = (uint2*)(rowcsr + (size_t)N_NODES * PAD); // [NBKT,BCAP] 16 MB
    float* dinv   = (float*)(binned + (size_t)NBKT * BCAP);   // [N]
    float* pooled = dinv + N_NODES;                           // [64*128]
    int*   gfill  = (int*)(pooled + NUM_GRAPHS * NFEAT);      // [NBKT]
    int*   cnt    = gfill + NBKT;                             // [N]
    ushort* W1b   = (ushort*)(cnt + N_NODES);                 // [128*128] bf16
    ushort* W2b   = W1b + NFEAT * NFEAT;                      // [128*128] bf16

    dim3 blk(256);
    int gN = (N_NODES + 255) / 256;
    int gW = (N_NODES + 3) / 4;
    int gG = (N_NODES + 63) / 64;
    int gB = (E + EPB - 1) / EPB;

    k_init0<<<gN, blk, 0, stream>>>(gfill, pooled);
    k_bin<<<gB, blk, 0, stream>>>(dstp, srcp, ew, gfill, binned, E);
    k_build<<<NBKT, blk, 0, stream>>>(binned, gfill, rowcsr, cnt, dinv, N_NODES);
    k_w2b<<<128, blk, 0, stream>>>(W1, W2, W1b);

    k_ln0<<<gW, blk, 0, stream>>>(x, ln0g, ln0b, A, N_NODES);
    k_gemm_mfma<<<gG, blk, 0, stream>>>(A, W1b, dinv, B, N_NODES);
    k_agg_ln<<<gW, blk, 0, stream>>>(B, rowcsr, cnt, dinv, b1, ln1g, ln1b, A, N_NODES);
    k_gemm_mfma<<<gG, blk, 0, stream>>>(A, W2b, dinv, B, N_NODES);
    k_agg_ln<<<gW, blk, 0, stream>>>(B, rowcsr, cnt, dinv, b2, ln2g, ln2b, A, N_NODES);
    k_pool<<<(N_NODES + 63) / 64, blk, 0, stream>>>(A, batch, pooled, N_NODES);
    k_final<<<NUM_GRAPHS, dim3(128), 0, stream>>>(pooled, Wc, bc, out);
}

// Round 9
// 394.665 us; speedup vs baseline: 1.2802x; 1.0375x over previous
//
#include <hip/hip_runtime.h>
#include <hip/hip_bf16.h>
#include <math.h>

#define N_NODES 100000
#define NFEAT 128
#define NCLASS 16
#define NUM_GRAPHS 64
#define LN_EPS 1e-5f
#define PAD 56        // max in-degree slots; Binomial(1.6M,1e-5) P(>=56) ~1e-9 overall
#define BSHIFT 7
#define NBKT 782      // ceil(100000/128)
#define BCAP 2560     // bucket capacity; mean 2046, sd ~45 -> +11 sigma
#define EPB 4096      // edges per k_bin block

typedef unsigned int uint;
typedef unsigned short ushort;
typedef short bf16x8 __attribute__((ext_vector_type(8)));
typedef float f32x4 __attribute__((ext_vector_type(4)));

__device__ __forceinline__ float wave_sum64(float v) {
#pragma unroll
    for (int m = 32; m >= 1; m >>= 1) v += __shfl_xor(v, m, 64);
    return v;
}

// bf16 helpers (bit-level, RNE)
__device__ __forceinline__ float bf_lo(uint u) { return __uint_as_float(u << 16); }
__device__ __forceinline__ float bf_hi(uint u) { return __uint_as_float(u & 0xffff0000u); }
__device__ __forceinline__ ushort f2bf(float f) {
    uint u = __float_as_uint(f);
    uint r = 0x7fffu + ((u >> 16) & 1u);
    return (ushort)((u + r) >> 16);
}
__device__ __forceinline__ uint pack2bf(float x, float y) {
    return ((uint)f2bf(y) << 16) | (uint)f2bf(x);
}
// 15-bit float (sign+exp8+mant6), RNE; exact for ew=1.0
__device__ __forceinline__ uint pk15(float f) {
    uint u = __float_as_uint(f);
    uint r = 0xFFFFu + ((u >> 17) & 1u);
    return (u + r) >> 17;
}
__device__ __forceinline__ float up15(uint w) {
    return __uint_as_float((w & 0x7FFFu) << 17);
}

__global__ void k_init0(int* __restrict__ gfill, float* __restrict__ pooled) {
    int i = blockIdx.x * 256 + threadIdx.x;
    if (i < NBKT) gfill[i] = 0;
    if (i < NUM_GRAPHS * NFEAT) pooled[i] = 0.0f;
}

// Bucketed binning: LDS histogram -> one global atomic per (block,bucket)
// run reservation -> grouped run writes into padded bucket buffer.
__global__ __launch_bounds__(256) void k_bin(const int* __restrict__ dst,
                                             const int* __restrict__ src,
                                             const float* __restrict__ ew,
                                             int* __restrict__ gfill,
                                             uint2* __restrict__ binned, int E) {
    __shared__ int lcnt[NBKT];
    __shared__ int lbase[NBKT];
    int t = threadIdx.x;
    int e0 = blockIdx.x * EPB;
    for (int i = t; i < NBKT; i += 256) lcnt[i] = 0;
    __syncthreads();
    int myb[16], myd[16];
#pragma unroll
    for (int i = 0; i < 16; ++i) {
        int e = e0 + i * 256 + t;
        int b = -1, d = 0;
        if (e < E) {
            d = dst[e];
            b = d >> BSHIFT;
            atomicAdd(&lcnt[b], 1);
        }
        myb[i] = b;
        myd[i] = d;
    }
    __syncthreads();
    for (int i = t; i < NBKT; i += 256) {
        int c = lcnt[i];
        lbase[i] = (c > 0) ? atomicAdd(&gfill[i], c) : 0;
        lcnt[i] = 0;  // reuse as local place counter
    }
    __syncthreads();
#pragma unroll
    for (int i = 0; i < 16; ++i) {
        int e = e0 + i * 256 + t;
        if (e >= E) continue;
        int b = myb[i];
        int ofs = lbase[b] + atomicAdd(&lcnt[b], 1);
        if (ofs < BCAP) {
            uint s = (uint)src[e];
            binned[(size_t)b * BCAP + ofs] =
                make_uint2(((uint)(myd[i] & 127) << 17) | s, __float_as_uint(ew[e]));
        }
    }
}

// One block per bucket (128 nodes): scatter records into LDS CSR
// (stride 57 vs bank conflicts), then full-line coalesced copy to global;
// compute cnt + dinv in-block.
__global__ __launch_bounds__(256) void k_build(const uint2* __restrict__ binned,
                                               const int* __restrict__ gfill,
                                               uint* __restrict__ rowcsr,
                                               int* __restrict__ cnt,
                                               float* __restrict__ dinv, int n) {
    __shared__ uint lcsr[128 * 57];   // 29184 B
    __shared__ int lc[128];
    int b = blockIdx.x, t = threadIdx.x;
    int node0 = b << BSHIFT;
    if (t < 128) lc[t] = 0;
    __syncthreads();
    int c = gfill[b];
    if (c > BCAP) c = BCAP;
    const uint2* rec = binned + (size_t)b * BCAP;
    for (int i = t; i < c; i += 256) {
        uint2 r = rec[i];
        int nl = (int)(r.x >> 17);
        int slot = atomicAdd(&lc[nl], 1);
        if (slot < PAD)
            lcsr[nl * 57 + slot] = ((r.x & 0x1FFFFu) << 15) | pk15(__uint_as_float(r.y));
    }
    __syncthreads();
    int nvalid = n - node0;
    if (nvalid > 128) nvalid = 128;
    if (nvalid <= 0) return;
    size_t gbase = (size_t)node0 * PAD;
    int wtot = nvalid * PAD;
    for (int i = t; i < wtot; i += 256) {
        int nl = i / PAD, sl = i - nl * PAD;
        rowcsr[gbase + i] = lcsr[nl * 57 + sl];
    }
    if (t < nvalid) {
        int cc = lc[t];
        if (cc > PAD) cc = PAD;
        float s = 0.0f;
        for (int r = 0; r < cc; ++r) s += up15(lcsr[t * 57 + r]);
        cnt[node0 + t] = cc;
        dinv[node0 + t] = rsqrtf(1.0f + s);
    }
}

// fp32 [2x 128x128] -> bf16 (both weight matrices in one launch)
__global__ void k_w2b(const float* __restrict__ W1, const float* __restrict__ W2,
                      ushort* __restrict__ Wb) {
    int i = blockIdx.x * 256 + threadIdx.x;
    if (i < NFEAT * NFEAT) Wb[i] = f2bf(W1[i]);
    else if (i < 2 * NFEAT * NFEAT) Wb[i] = f2bf(W2[i - NFEAT * NFEAT]);
}

// LN0 with dinv fold: u0 = dinv * LN0(x). fp32 in -> bf16 out.
__global__ void k_ln0(const float* __restrict__ in, const float* __restrict__ g,
                      const float* __restrict__ b, const float* __restrict__ dinv,
                      ushort* __restrict__ out, int n) {
    int row = blockIdx.x * 4 + (threadIdx.x >> 6);
    if (row >= n) return;
    int lane = threadIdx.x & 63;
    float2 v = *(const float2*)(in + (size_t)row * NFEAT + 2 * lane);
    float mean = wave_sum64(v.x + v.y) * (1.0f / NFEAT);
    float dx = v.x - mean, dy = v.y - mean;
    float var = wave_sum64(dx * dx + dy * dy) * (1.0f / NFEAT);
    float rs = rsqrtf(var + LN_EPS);
    float2 gg = *(const float2*)(g + 2 * lane);
    float2 bb = *(const float2*)(b + 2 * lane);
    float di = dinv[row];
    float ox = (dx * rs * gg.x + bb.x) * di;
    float oy = (dy * rs * gg.y + bb.y) * di;
    *(uint*)(out + (size_t)row * NFEAT + 2 * lane) = pack2bf(ox, oy);
}

// x8-unrolled edge gather for one node: acc += sum ew * U[src]
__device__ __forceinline__ void gather_node(const ushort* __restrict__ U,
                                            const uint* __restrict__ rowcsr,
                                            int c, size_t base, int lane,
                                            float& ax, float& ay) {
    for (int e0 = 0; e0 < c; e0 += 64) {
        int c2 = c - e0;
        if (c2 > 64) c2 = 64;
        uint meta = 0;
        if (lane < c2) meta = rowcsr[base + e0 + lane];
        int j = 0;
        for (; j + 8 <= c2; j += 8) {
            uint mw[8];
#pragma unroll
            for (int k = 0; k < 8; ++k) mw[k] = __shfl(meta, j + k, 64);
            uint uu[8];
#pragma unroll
            for (int k = 0; k < 8; ++k)
                uu[k] = *(const uint*)(U + (size_t)(mw[k] >> 15) * NFEAT + 2 * lane);
#pragma unroll
            for (int k = 0; k < 8; ++k) {
                float w = up15(mw[k]);
                ax = fmaf(bf_lo(uu[k]), w, ax);
                ay = fmaf(bf_hi(uu[k]), w, ay);
            }
        }
        if (j + 4 <= c2) {
            uint mw[4];
#pragma unroll
            for (int k = 0; k < 4; ++k) mw[k] = __shfl(meta, j + k, 64);
            uint uu[4];
#pragma unroll
            for (int k = 0; k < 4; ++k)
                uu[k] = *(const uint*)(U + (size_t)(mw[k] >> 15) * NFEAT + 2 * lane);
#pragma unroll
            for (int k = 0; k < 4; ++k) {
                float w = up15(mw[k]);
                ax = fmaf(bf_lo(uu[k]), w, ax);
                ay = fmaf(bf_hi(uu[k]), w, ay);
            }
            j += 4;
        }
        for (; j < c2; ++j) {
            uint mw = __shfl(meta, j, 64);
            float w = up15(mw);
            uint u = *(const uint*)(U + (size_t)(mw >> 15) * NFEAT + 2 * lane);
            ax = fmaf(bf_lo(u), w, ax);
            ay = fmaf(bf_hi(u), w, ay);
        }
    }
}

// Fused GCN conv layer (aggregation commuted before GEMM):
//   g_d = dinv_d * (u_d + sum ew * u_s)          (phase A, gather -> LDS)
//   t   = g @ W^T + bias                          (phase B, MFMA)
//   h   = relu(LN(t))
//   LAST=0: write u = dinv * h (bf16).  LAST=1: pool h per graph (atomics).
// Block = 256 thr = 4 waves; wave owns 16 rows end-to-end (no barriers).
template <int LAST>
__global__ __launch_bounds__(256) void k_conv(const ushort* __restrict__ U,
                                              const ushort* __restrict__ Wb,
                                              const uint* __restrict__ rowcsr,
                                              const int* __restrict__ cnt,
                                              const float* __restrict__ dinv,
                                              const float* __restrict__ bias,
                                              const float* __restrict__ lng,
                                              const float* __restrict__ lnb,
                                              const int* __restrict__ batch,
                                              ushort* __restrict__ Uout,
                                              float* __restrict__ pooled, int n) {
    __shared__ uint lg[64 * 68];   // 17.4 KB; [local_row][feat_pair], stride 68
    int tid = threadIdx.x;
    int wave = tid >> 6, lane = tid & 63;
    int rbase = blockIdx.x * 64 + wave * 16;

    // ---- phase A: gather 16 rows into LDS (bf16-packed, dinv_d applied) ----
    for (int i = 0; i < 16; ++i) {
        int node = rbase + i;
        uint packed = 0;
        if (node < n) {
            float di = dinv[node];
            uint tu = *(const uint*)(U + (size_t)node * NFEAT + 2 * lane);
            float ax = bf_lo(tu), ay = bf_hi(tu);
            int c = cnt[node];
            if (c > PAD) c = PAD;
            gather_node(U, rowcsr, c, (size_t)node * PAD, lane, ax, ay);
            packed = pack2bf(di * ax, di * ay);
        }
        lg[(wave * 16 + i) * 68 + lane] = packed;
    }

    // ---- phase B: MFMA 16x128 tile (wave-local rows) ----
    int m = lane & 15, q = lane >> 4;   // frag: [row=m][k=q*8+j]
    bf16x8 a[4];
#pragma unroll
    for (int c = 0; c < 4; ++c)
        a[c] = *(const bf16x8*)&lg[(wave * 16 + m) * 68 + c * 16 + q * 4];
    float accs[8][4];
#pragma unroll
    for (int t = 0; t < 8; ++t) {
        const ushort* bp = Wb + (size_t)(t * 16 + m) * NFEAT + q * 8;
        f32x4 acc = {0.0f, 0.0f, 0.0f, 0.0f};
        acc = __builtin_amdgcn_mfma_f32_16x16x32_bf16(a[0], *(const bf16x8*)(bp), acc, 0, 0, 0);
        acc = __builtin_amdgcn_mfma_f32_16x16x32_bf16(a[1], *(const bf16x8*)(bp + 32), acc, 0, 0, 0);
        acc = __builtin_amdgcn_mfma_f32_16x16x32_bf16(a[2], *(const bf16x8*)(bp + 64), acc, 0, 0, 0);
        acc = __builtin_amdgcn_mfma_f32_16x16x32_bf16(a[3], *(const bf16x8*)(bp + 96), acc, 0, 0, 0);
#pragma unroll
        for (int r = 0; r < 4; ++r) accs[t][r] = acc[r];
    }
    float bs[8], gm[8], bm[8];
#pragma unroll
    for (int t = 0; t < 8; ++t) {
        bs[t] = bias[t * 16 + m];
        gm[t] = lng[t * 16 + m];
        bm[t] = lnb[t * 16 + m];
    }
    // ---- LN + ReLU per row (16-lane shfl_xor reductions over m-group) ----
#pragma unroll
    for (int r = 0; r < 4; ++r) {
        int row = rbase + q * 4 + r;
        float s = 0.0f;
#pragma unroll
        for (int t = 0; t < 8; ++t) s += accs[t][r] + bs[t];
#pragma unroll
        for (int mk = 1; mk <= 8; mk <<= 1) s += __shfl_xor(s, mk, 64);
        float mean = s * (1.0f / NFEAT);
        float v2 = 0.0f;
#pragma unroll
        for (int t = 0; t < 8; ++t) {
            float d = accs[t][r] + bs[t] - mean;
            v2 += d * d;
        }
#pragma unroll
        for (int mk = 1; mk <= 8; mk <<= 1) v2 += __shfl_xor(v2, mk, 64);
        float rs = rsqrtf(v2 * (1.0f / NFEAT) + LN_EPS);
        if (row < n) {
            if (!LAST) {
                float di = dinv[row];
#pragma unroll
                for (int t = 0; t < 8; ++t) {
                    float h = fmaxf((accs[t][r] + bs[t] - mean) * rs * gm[t] + bm[t], 0.0f);
                    Uout[(size_t)row * NFEAT + t * 16 + m] = f2bf(h * di);
                }
            } else {
                ushort* lh = (ushort*)lg;
#pragma unroll
                for (int t = 0; t < 8; ++t) {
                    float h = fmaxf((accs[t][r] + bs[t] - mean) * rs * gm[t] + bm[t], 0.0f);
                    lh[(wave * 16 + q * 4 + r) * 136 + t * 16 + m] = f2bf(h);
                }
            }
        }
    }
    // ---- pool phase (LAST only): wave sums its 16 rows, flush on graph change ----
    if (LAST) {
        float accx = 0.0f, accy = 0.0f;
        int cur = -1;
        for (int i = 0; i < 16; ++i) {
            int node = rbase + i;
            if (node >= n) break;
            int g = batch[node];
            if (g != cur) {
                if (cur >= 0) {
                    unsafeAtomicAdd(&pooled[cur * NFEAT + 2 * lane], accx);
                    unsafeAtomicAdd(&pooled[cur * NFEAT + 2 * lane + 1], accy);
                }
                accx = 0.0f; accy = 0.0f;
                cur = g;
            }
            uint u = lg[(wave * 16 + i) * 68 + lane];
            accx += bf_lo(u);
            accy += bf_hi(u);
        }
        if (cur >= 0) {
            unsafeAtomicAdd(&pooled[cur * NFEAT + 2 * lane], accx);
            unsafeAtomicAdd(&pooled[cur * NFEAT + 2 * lane + 1], accy);
        }
    }
}

// logits = pooled @ Wc^T + bc; log_softmax. One block per graph.
__global__ void k_final(const float* __restrict__ pooled, const float* __restrict__ Wc,
                        const float* __restrict__ bc, float* __restrict__ out) {
    __shared__ float p[128];
    __shared__ float lg[NCLASS];
    int g = blockIdx.x, t = threadIdx.x;
    p[t] = pooled[g * 128 + t];
    __syncthreads();
    if (t < NCLASS) {
        float s = bc[t];
        for (int k = 0; k < 128; ++k) s = fmaf(p[k], Wc[t * 128 + k], s);
        lg[t] = s;
    }
    __syncthreads();
    if (t == 0) {
        float m = -1e30f;
        for (int j = 0; j < NCLASS; ++j) m = fmaxf(m, lg[j]);
        float sum = 0.0f;
        for (int j = 0; j < NCLASS; ++j) sum += expf(lg[j] - m);
        float l = logf(sum);
        for (int j = 0; j < NCLASS; ++j) out[g * NCLASS + j] = lg[j] - m - l;
    }
}

extern "C" void kernel_launch(void* const* d_in, const int* in_sizes, int n_in,
                              void* d_out, int out_size, void* d_ws, size_t ws_size,
                              hipStream_t stream) {
    const float* x    = (const float*)d_in[0];
    const int*   ei   = (const int*)d_in[1];
    const int*   batch= (const int*)d_in[2];
    const float* ew   = (const float*)d_in[3];
    const float* ln0g = (const float*)d_in[4];
    const float* ln0b = (const float*)d_in[5];
    const float* W1   = (const float*)d_in[6];
    const float* b1   = (const float*)d_in[7];
    const float* ln1g = (const float*)d_in[8];
    const float* ln1b = (const float*)d_in[9];
    const float* W2   = (const float*)d_in[10];
    const float* b2   = (const float*)d_in[11];
    const float* ln2g = (const float*)d_in[12];
    const float* ln2b = (const float*)d_in[13];
    const float* Wc   = (const float*)d_in[14];
    const float* bc   = (const float*)d_in[15];
    float* out = (float*)d_out;

    int E = in_sizes[1] / 2;
    const int* srcp = ei;
    const int* dstp = ei + E;

    // ws layout (~90 MB)
    ushort* A     = (ushort*)d_ws;                            // [N,128] bf16 (u0/u1)
    ushort* B     = A + (size_t)N_NODES * NFEAT;              // [N,128] bf16
    uint*  rowcsr = (uint*)(B + (size_t)N_NODES * NFEAT);     // [N,PAD] 22.4 MB
    uint2* binned = (uint2*)(rowcsr + (size_t)N_NODES * PAD); // [NBKT,BCAP] 16 MB
    float* dinv   = (float*)(binned + (size_t)NBKT * BCAP);   // [N]
    float* pooled = dinv + N_NODES;                           // [64*128]
    int*   gfill  = (int*)(pooled + NUM_GRAPHS * NFEAT);      // [NBKT]
    int*   cnt    = gfill + NBKT;                             // [N]
    ushort* W1b   = (ushort*)(cnt + N_NODES);                 // [128*128] bf16
    ushort* W2b   = W1b + NFEAT * NFEAT;                      // [128*128] bf16

    dim3 blk(256);
    int gN = (N_NODES + 255) / 256;
    int gW = (N_NODES + 3) / 4;
    int gC = (N_NODES + 63) / 64;
    int gB = (E + EPB - 1) / EPB;

    k_init0<<<gN, blk, 0, stream>>>(gfill, pooled);
    k_bin<<<gB, blk, 0, stream>>>(dstp, srcp, ew, gfill, binned, E);
    k_build<<<NBKT, blk, 0, stream>>>(binned, gfill, rowcsr, cnt, dinv, N_NODES);
    k_w2b<<<128, blk, 0, stream>>>(W1, W2, W1b);

    // u0 = dinv * LN0(x) -> A
    k_ln0<<<gW, blk, 0, stream>>>(x, ln0g, ln0b, dinv, A, N_NODES);
    // conv1: gather(u0) -> MFMA W1 -> LN1+ReLU -> u1 -> B
    k_conv<0><<<gC, blk, 0, stream>>>(A, W1b, rowcsr, cnt, dinv, b1, ln1g, ln1b,
                                      batch, B, pooled, N_NODES);
    // conv2: gather(u1) -> MFMA W2 -> LN2+ReLU -> pool (no global h2)
    k_conv<1><<<gC, blk, 0, stream>>>(B, W2b, rowcsr, cnt, dinv, b2, ln2g, ln2b,
                                      batch, A, pooled, N_NODES);
    k_final<<<NUM_GRAPHS, dim3(128), 0, stream>>>(pooled, Wc, bc, out);
}